// Round 1
// baseline (274.969 us; speedup 1.0000x reference)
//
#include <hip/hip_runtime.h>
#include <hip/hip_bf16.h>
#include <math.h>

#define BB 8
#define TT 96
#define SS 192
#define DIN 512
#define DM 512

__device__ __forceinline__ float fast_tanh(float x) {
    float cx = fminf(fmaxf(x, -15.f), 15.f);
    float e = __expf(2.f * cx);                       // v_exp_f32 path
    return 1.f - 2.f * __builtin_amdgcn_rcpf(e + 1.f); // v_rcp_f32
}

// out[r][n] = bias[n] + sum_k concat(A1,A2)[r][k] * W[n][k]
// A1: [M][K1], A2: [M][K2] (may be null if K2==0), W: [N][K1+K2] row-major.
// Tile: 64x64 output per block, 256 threads, 4x4 microtile, K-step 16.
__global__ __launch_bounds__(256)
void gemm_rowdot(const float* __restrict__ A1, int K1,
                 const float* __restrict__ A2, int K2,
                 const float* __restrict__ W,
                 const float* __restrict__ bias,
                 float* __restrict__ out,
                 int M, int N)
{
    const int K = K1 + K2;
    __shared__ float Ast[16][64];  // [k][row] transposed for b128 fragment reads
    __shared__ float Wst[16][64];
    const int tid = threadIdx.x;
    const int bm = blockIdx.x * 64;
    const int bn = blockIdx.y * 64;
    const int ty = tid >> 4, tx = tid & 15;
    float acc[4][4] = {};

    for (int k0 = 0; k0 < K; k0 += 16) {
        #pragma unroll
        for (int i = 0; i < 4; ++i) {
            int idx = tid + i * 256;
            int r = idx >> 4, kc = idx & 15;
            int gk = k0 + kc;
            float val;
            if (gk < K1) val = A1[(size_t)(bm + r) * K1 + gk];
            else         val = A2[(size_t)(bm + r) * K2 + (gk - K1)];
            Ast[kc][r] = val;
        }
        #pragma unroll
        for (int i = 0; i < 4; ++i) {
            int idx = tid + i * 256;
            int r = idx >> 4, kc = idx & 15;
            Wst[kc][r] = W[(size_t)(bn + r) * K + (k0 + kc)];
        }
        __syncthreads();
        #pragma unroll
        for (int kk = 0; kk < 16; ++kk) {
            float a[4], w[4];
            #pragma unroll
            for (int i = 0; i < 4; ++i) a[i] = Ast[kk][ty * 4 + i];
            #pragma unroll
            for (int j = 0; j < 4; ++j) w[j] = Wst[kk][tx * 4 + j];
            #pragma unroll
            for (int i = 0; i < 4; ++i)
                #pragma unroll
                for (int j = 0; j < 4; ++j)
                    acc[i][j] += a[i] * w[j];
        }
        __syncthreads();
    }
    #pragma unroll
    for (int i = 0; i < 4; ++i) {
        int r = bm + ty * 4 + i;
        #pragma unroll
        for (int j = 0; j < 4; ++j) {
            int n = bn + tx * 4 + j;
            float bv = bias ? bias[n] : 0.f;
            out[(size_t)r * N + n] = acc[i][j] + bv;
        }
    }
}

// One block per (b,t). Computes scores over s (tanh-MLP), masked softmax,
// writes align_vectors, accumulates context c[b,t,:].
__global__ __launch_bounds__(256)
void attn_core(const float* __restrict__ wq,        // [B*T][DM]
               const float* __restrict__ uh,        // [B*S][DM]
               const float* __restrict__ v,         // [DM]
               const float* __restrict__ mems,      // [B*S][DM]
               const int*   __restrict__ mem_masks, // [B]
               float* __restrict__ align_out,       // [B*T][S]
               float* __restrict__ c_out)           // [B*T][DM]
{
    __shared__ float sq[DM];
    __shared__ float sv[DM];
    __shared__ float s_align[SS];
    __shared__ float s_max, s_sum;

    const int row = blockIdx.x;   // b*T + t
    const int b = row / TT;
    const int tid = threadIdx.x;
    const int lane = tid & 63;
    const int wid = tid >> 6;
    const int len = mem_masks[b];

    for (int i = tid; i < DM; i += 256) {
        sq[i] = wq[(size_t)row * DM + i];
        sv[i] = v[i];
    }
    __syncthreads();

    // scores: one wave per s
    for (int s = wid; s < SS; s += 4) {
        float val;
        if (s < len) {
            const float* urow = uh + ((size_t)b * SS + s) * DM;
            float part = 0.f;
            #pragma unroll
            for (int j = 0; j < DM / 64; ++j) {
                int m = lane + j * 64;
                float x = sq[m] + urow[m];
                part += sv[m] * fast_tanh(x);
            }
            #pragma unroll
            for (int off = 32; off > 0; off >>= 1)
                part += __shfl_down(part, off);
            val = part;
        } else {
            val = -INFINITY;
        }
        if (lane == 0) s_align[s] = val;
    }
    __syncthreads();

    // softmax: max
    if (tid < 64) {
        float m = -INFINITY;
        for (int s = tid; s < SS; s += 64) m = fmaxf(m, s_align[s]);
        #pragma unroll
        for (int off = 32; off > 0; off >>= 1)
            m = fmaxf(m, __shfl_down(m, off));
        if (tid == 0) s_max = m;
    }
    __syncthreads();
    // exp + sum
    if (tid < 64) {
        float mx = s_max;
        float sum = 0.f;
        for (int s = tid; s < SS; s += 64) {
            float e = __expf(s_align[s] - mx);  // exp(-inf)=0 for masked
            s_align[s] = e;
            sum += e;
        }
        #pragma unroll
        for (int off = 32; off > 0; off >>= 1)
            sum += __shfl_down(sum, off);
        if (tid == 0) s_sum = sum;
    }
    __syncthreads();

    const float inv = 1.0f / s_sum;
    if (tid < SS)
        align_out[(size_t)row * SS + tid] = s_align[tid] * inv;

    // context: each thread owns d = tid and tid+256
    const float* memb = mems + (size_t)b * SS * DM;
    float acc0 = 0.f, acc1 = 0.f;
    for (int s = 0; s < len; ++s) {
        float p = s_align[s];
        acc0 += p * memb[(size_t)s * DM + tid];
        acc1 += p * memb[(size_t)s * DM + tid + 256];
    }
    c_out[(size_t)row * DM + tid]       = acc0 * inv;
    c_out[(size_t)row * DM + tid + 256] = acc1 * inv;
}

extern "C" void kernel_launch(void* const* d_in, const int* in_sizes, int n_in,
                              void* d_out, int out_size, void* d_ws, size_t ws_size,
                              hipStream_t stream) {
    (void)in_sizes; (void)n_in; (void)out_size; (void)ws_size;
    const float* inputs = (const float*)d_in[0];   // [B,T,DIN]
    const float* mems   = (const float*)d_in[1];   // [B,S,DM]
    const int*   masks  = (const int*)  d_in[2];   // [B]
    const float* Wq     = (const float*)d_in[3];   // [DM,DIN]
    const float* Wc     = (const float*)d_in[4];   // [DM,DM]
    const float* bc     = (const float*)d_in[5];   // [DM]
    const float* v      = (const float*)d_in[6];   // [DM]
    const float* Wout   = (const float*)d_in[7];   // [DIN, DM+DIN]
    const float* bout   = (const float*)d_in[8];   // [DIN]

    float* wq_ws = (float*)d_ws;                         // [B*T][DM]
    float* uh_ws = wq_ws + (size_t)BB * TT * DM;         // [B*S][DM]
    float* c_ws  = uh_ws + (size_t)BB * SS * DM;         // [B*T][DM]

    float* attn_h    = (float*)d_out;                    // [B*T][DIN]
    float* align_out = attn_h + (size_t)BB * TT * DIN;   // [B*T][S]

    // wq = inputs @ Wq^T            (M=768, N=512, K=512)
    gemm_rowdot<<<dim3((BB * TT) / 64, DM / 64), 256, 0, stream>>>(
        inputs, DIN, nullptr, 0, Wq, nullptr, wq_ws, BB * TT, DM);
    // uh = mems @ Wc^T + bc         (M=1536, N=512, K=512)
    gemm_rowdot<<<dim3((BB * SS) / 64, DM / 64), 256, 0, stream>>>(
        mems, DM, nullptr, 0, Wc, bc, uh_ws, BB * SS, DM);
    // scores + softmax + context
    attn_core<<<BB * TT, 256, 0, stream>>>(
        wq_ws, uh_ws, v, mems, masks, align_out, c_ws);
    // attn_h = [c, inputs] @ Wout^T + bout   (M=768, N=512, K=1024)
    gemm_rowdot<<<dim3((BB * TT) / 64, DIN / 64), 256, 0, stream>>>(
        c_ws, DM, inputs, DIN, Wout, bout, attn_h, BB * TT, DIN);
}

// Round 2
// 134.452 us; speedup vs baseline: 2.0451x; 2.0451x over previous
//
#include <hip/hip_runtime.h>
#include <math.h>

#define BB 8
#define TT 96
#define SS 192
#define DIN 512
#define DM 512

typedef short short8 __attribute__((ext_vector_type(8)));
typedef float f32x4 __attribute__((ext_vector_type(4)));

__device__ __forceinline__ unsigned short f2bf(float f) {
    unsigned int u = __float_as_uint(f);
    unsigned int r = u + 0x7FFFu + ((u >> 16) & 1u);   // RNE
    return (unsigned short)(r >> 16);
}
__device__ __forceinline__ float bf2f(unsigned short h) {
    return __uint_as_float(((unsigned int)h) << 16);
}

__device__ __forceinline__ void load_lds16(const void* g, void* l) {
    __builtin_amdgcn_global_load_lds((__attribute__((address_space(1))) void*)g,
                                     (__attribute__((address_space(3))) void*)l,
                                     16, 0, 0);
}

// ---------------- prep: fp32 -> bf16 conversion of 5 arrays ----------------
// sizes: inputs 393216, mems 786432, Wq 262144, Wc 262144, Wout 524288
// blocks (2048 elems each): 192, 384, 128, 128, 256 ; cum 192,576,704,832,1088
__global__ __launch_bounds__(256) void prep_cvt(
    const float* __restrict__ s0, const float* __restrict__ s1,
    const float* __restrict__ s2, const float* __restrict__ s3,
    const float* __restrict__ s4,
    unsigned short* __restrict__ d0, unsigned short* __restrict__ d1,
    unsigned short* __restrict__ d2, unsigned short* __restrict__ d3,
    unsigned short* __restrict__ d4)
{
    int bid = blockIdx.x;
    const float* s; unsigned short* d; int base;
    if (bid < 192)      { s = s0; d = d0; base = bid * 2048; }
    else if (bid < 576) { s = s1; d = d1; base = (bid - 192) * 2048; }
    else if (bid < 704) { s = s2; d = d2; base = (bid - 576) * 2048; }
    else if (bid < 832) { s = s3; d = d3; base = (bid - 704) * 2048; }
    else                { s = s4; d = d4; base = (bid - 832) * 2048; }
    int idx = base + threadIdx.x * 8;
    float4 a = *(const float4*)(s + idx);
    float4 b = *(const float4*)(s + idx + 4);
    short8 o;
    o[0] = (short)f2bf(a.x); o[1] = (short)f2bf(a.y);
    o[2] = (short)f2bf(a.z); o[3] = (short)f2bf(a.w);
    o[4] = (short)f2bf(b.x); o[5] = (short)f2bf(b.y);
    o[6] = (short)f2bf(b.z); o[7] = (short)f2bf(b.w);
    *(short8*)(d + idx) = o;
}

// ---------------- bf16 MFMA GEMM tile: out[m][n] = sum_k A[m][k]*W[n][k] ----
// 64x64 tile, 256 threads (4 waves), K-chunk 32, double-buffered LDS via
// global_load_lds width=16. A = concat(A1[K1], A2[K-K1]) along K.
__device__ __forceinline__ void gemm_tile(
    unsigned short* As, unsigned short* Ws,   // shared, 2*2048 ushorts each
    const unsigned short* __restrict__ A1, const unsigned short* __restrict__ A2,
    int K1, const unsigned short* __restrict__ W, const float* __restrict__ bias,
    float* __restrict__ outF, unsigned short* __restrict__ outB,
    int bm, int bn, int N, int K)
{
    const int tid = threadIdx.x;
    const int r  = tid >> 2;          // 0..63 : tile row loaded by this thread
    const int kc = (tid & 3) * 8;     // k-offset within chunk
    const int lane = tid & 63, wv = tid >> 6;
    const int quad = lane >> 4, mrow = lane & 15;

    f32x4 acc0 = {0,0,0,0}, acc1 = {0,0,0,0}, acc2 = {0,0,0,0}, acc3 = {0,0,0,0};

    const unsigned short* wrow = W + (size_t)(bn + r) * K;
    auto asrc = [&](int gk) -> const unsigned short* {
        return (gk < K1) ? (A1 + (size_t)(bm + r) * K1 + gk)
                         : (A2 + (size_t)(bm + r) * (K - K1) + (gk - K1));
    };

    load_lds16(asrc(kc), As + tid * 8);
    load_lds16(wrow + kc, Ws + tid * 8);
    __syncthreads();

    const int NC = K >> 5;
    for (int c = 0; c < NC; ++c) {
        const int cur = (c & 1) * 2048;
        if (c + 1 < NC) {
            const int nxt = 2048 - cur;
            int gk = ((c + 1) << 5) + kc;
            load_lds16(asrc(gk), As + nxt + tid * 8);
            load_lds16(wrow + gk, Ws + nxt + tid * 8);
        }
        short8 av = *(const short8*)(As + cur + (wv * 16 + mrow) * 32 + quad * 8);
        short8 b0 = *(const short8*)(Ws + cur + (mrow) * 32 + quad * 8);
        short8 b1 = *(const short8*)(Ws + cur + (16 + mrow) * 32 + quad * 8);
        short8 b2 = *(const short8*)(Ws + cur + (32 + mrow) * 32 + quad * 8);
        short8 b3 = *(const short8*)(Ws + cur + (48 + mrow) * 32 + quad * 8);
        acc0 = __builtin_amdgcn_mfma_f32_16x16x32_bf16(av, b0, acc0, 0, 0, 0);
        acc1 = __builtin_amdgcn_mfma_f32_16x16x32_bf16(av, b1, acc1, 0, 0, 0);
        acc2 = __builtin_amdgcn_mfma_f32_16x16x32_bf16(av, b2, acc2, 0, 0, 0);
        acc3 = __builtin_amdgcn_mfma_f32_16x16x32_bf16(av, b3, acc3, 0, 0, 0);
        __syncthreads();   // drains prefetch vmcnt + protects LDS reuse
    }

    f32x4 accs[4] = {acc0, acc1, acc2, acc3};
    #pragma unroll
    for (int ct = 0; ct < 4; ++ct) {
        int col = bn + ct * 16 + mrow;
        float bv = bias ? bias[col] : 0.0f;
        #pragma unroll
        for (int rg = 0; rg < 4; ++rg) {
            int rw = bm + wv * 16 + quad * 4 + rg;   // C/D: col=lane&15, row=quad*4+reg
            float val = accs[ct][rg] + bv;
            if (outF) outF[(size_t)rw * N + col] = val;
            else      outB[(size_t)rw * N + col] = f2bf(val);
        }
    }
}

// fused wq + uh projection: blocks [0,96) -> wq (M=768), [96,288) -> uh (M=1536)
__global__ __launch_bounds__(256) void proj_gemm(
    const unsigned short* __restrict__ inputs_bf,
    const unsigned short* __restrict__ mems_bf,
    const unsigned short* __restrict__ Wq_bf,
    const unsigned short* __restrict__ Wc_bf,
    const float* __restrict__ bc,
    unsigned short* __restrict__ wq_o,
    unsigned short* __restrict__ uh_o)
{
    __shared__ __align__(16) unsigned short As[2 * 2048];
    __shared__ __align__(16) unsigned short Ws[2 * 2048];
    int bid = blockIdx.x;
    if (bid < 96) {
        gemm_tile(As, Ws, inputs_bf, inputs_bf, DIN, Wq_bf, nullptr, nullptr, wq_o,
                  (bid >> 3) * 64, (bid & 7) * 64, DM, DIN);
    } else {
        bid -= 96;
        gemm_tile(As, Ws, mems_bf, mems_bf, DM, Wc_bf, bc, nullptr, uh_o,
                  (bid >> 3) * 64, (bid & 7) * 64, DM, DM);
    }
}

// attn_h = concat(c, inputs) @ Wout^T + bout   (M=768, N=512, K=1024)
__global__ __launch_bounds__(256) void out_gemm(
    const unsigned short* __restrict__ c_bf,
    const unsigned short* __restrict__ inputs_bf,
    const unsigned short* __restrict__ Wout_bf,
    const float* __restrict__ bout,
    float* __restrict__ attn_h)
{
    __shared__ __align__(16) unsigned short As[2 * 2048];
    __shared__ __align__(16) unsigned short Ws[2 * 2048];
    int bid = blockIdx.x;
    gemm_tile(As, Ws, c_bf, inputs_bf, DM, Wout_bf, bout, attn_h, nullptr,
              (bid >> 3) * 64, (bid & 7) * 64, DIN, DM + DIN);
}

// ---------------- fused scores + softmax + context ----------------
// one block per (b,t); lane owns m = lane*8..lane*8+8 (q,v in registers)
__global__ __launch_bounds__(256) void attn_core(
    const unsigned short* __restrict__ wq,     // [B*T][DM] bf16
    const unsigned short* __restrict__ uh,     // [B*S][DM] bf16
    const float* __restrict__ v,               // [DM] fp32
    const unsigned short* __restrict__ mems,   // [B*S][DM] bf16
    const int* __restrict__ masks,             // [B]
    float* __restrict__ align_out,             // [B*T][S] fp32
    unsigned short* __restrict__ c_out)        // [B*T][DM] bf16
{
    __shared__ float s_align[SS];
    __shared__ float s_stat;
    const int row = blockIdx.x, b = row / TT;
    const int tid = threadIdx.x, lane = tid & 63, wid = tid >> 6;
    const int len = masks[b];

    float qf[8], vf[8];
    {
        short8 q = *(const short8*)(wq + (size_t)row * DM + lane * 8);
        float4 v0 = *(const float4*)(v + lane * 8);
        float4 v1 = *(const float4*)(v + lane * 8 + 4);
        #pragma unroll
        for (int j = 0; j < 8; ++j) qf[j] = bf2f((unsigned short)q[j]);
        vf[0] = v0.x; vf[1] = v0.y; vf[2] = v0.z; vf[3] = v0.w;
        vf[4] = v1.x; vf[5] = v1.y; vf[6] = v1.z; vf[7] = v1.w;
    }

    for (int s = wid; s < SS; s += 4) {
        float val = -INFINITY;
        if (s < len) {
            short8 u = *(const short8*)(uh + ((size_t)b * SS + s) * DM + lane * 8);
            float part = 0.f;
            #pragma unroll
            for (int j = 0; j < 8; ++j) {
                float x = qf[j] + bf2f((unsigned short)u[j]);
                // exact tanh: 1 - 2/(exp2(x*2/ln2)+1)
                float e = __builtin_amdgcn_exp2f(x * 2.885390082f);
                float th = fmaf(-2.f, __builtin_amdgcn_rcpf(e + 1.f), 1.f);
                part = fmaf(vf[j], th, part);
            }
            #pragma unroll
            for (int off = 32; off; off >>= 1)
                part += __shfl_xor(part, off);
            val = part;
        }
        if (lane == 0) s_align[s] = val;
    }
    __syncthreads();

    if (tid < 64) {
        float m = fmaxf(fmaxf(s_align[tid], s_align[tid + 64]), s_align[tid + 128]);
        #pragma unroll
        for (int off = 32; off; off >>= 1) m = fmaxf(m, __shfl_xor(m, off));
        float e0 = __builtin_amdgcn_exp2f((s_align[tid]       - m) * 1.44269504f);
        float e1 = __builtin_amdgcn_exp2f((s_align[tid + 64]  - m) * 1.44269504f);
        float e2 = __builtin_amdgcn_exp2f((s_align[tid + 128] - m) * 1.44269504f);
        s_align[tid] = e0; s_align[tid + 64] = e1; s_align[tid + 128] = e2;
        float sum = e0 + e1 + e2;
        #pragma unroll
        for (int off = 32; off; off >>= 1) sum += __shfl_xor(sum, off);
        if (tid == 0) s_stat = 1.0f / sum;
    }
    __syncthreads();
    const float inv = s_stat;
    if (tid < SS) align_out[(size_t)row * SS + tid] = s_align[tid] * inv;

    // context: thread owns dims 2*tid, 2*tid+1
    float a0 = 0.f, a1 = 0.f;
    const unsigned short* mb = mems + (size_t)b * SS * DM;
    for (int s = 0; s < len; ++s) {
        float p = s_align[s];
        unsigned int u = *(const unsigned int*)(mb + (size_t)s * DM + tid * 2);
        a0 = fmaf(p, __uint_as_float(u << 16), a0);
        a1 = fmaf(p, __uint_as_float(u & 0xFFFF0000u), a1);
    }
    unsigned int pack = ((unsigned int)f2bf(a1 * inv) << 16) | (unsigned int)f2bf(a0 * inv);
    *(unsigned int*)(c_out + (size_t)row * DM + tid * 2) = pack;
}

extern "C" void kernel_launch(void* const* d_in, const int* in_sizes, int n_in,
                              void* d_out, int out_size, void* d_ws, size_t ws_size,
                              hipStream_t stream) {
    (void)in_sizes; (void)n_in; (void)out_size; (void)ws_size;
    const float* inputs = (const float*)d_in[0];
    const float* mems   = (const float*)d_in[1];
    const int*   masks  = (const int*)  d_in[2];
    const float* Wq     = (const float*)d_in[3];
    const float* Wc     = (const float*)d_in[4];
    const float* bc     = (const float*)d_in[5];
    const float* v      = (const float*)d_in[6];
    const float* Wout   = (const float*)d_in[7];
    const float* bout   = (const float*)d_in[8];

    unsigned short* p = (unsigned short*)d_ws;
    unsigned short* inputs_bf = p;            p += 393216;   // B*T*DIN
    unsigned short* mems_bf   = p;            p += 786432;   // B*S*DM
    unsigned short* Wq_bf     = p;            p += 262144;
    unsigned short* Wc_bf     = p;            p += 262144;
    unsigned short* Wout_bf   = p;            p += 524288;
    unsigned short* uh_bf     = p;            p += 786432;
    unsigned short* wq_bf     = p;            p += 393216;   // aliased as c_bf
    unsigned short* c_bf      = wq_bf;        // safe: block reads wq[row] before writing c[row]

    float* attn_h    = (float*)d_out;                    // [768][512]
    float* align_out = attn_h + (size_t)BB * TT * DIN;   // [768][192]

    prep_cvt<<<1088, 256, 0, stream>>>(inputs, mems, Wq, Wc, Wout,
                                       inputs_bf, mems_bf, Wq_bf, Wc_bf, Wout_bf);
    proj_gemm<<<288, 256, 0, stream>>>(inputs_bf, mems_bf, Wq_bf, Wc_bf, bc,
                                       wq_bf, uh_bf);
    attn_core<<<BB * TT, 256, 0, stream>>>(wq_bf, uh_bf, v, mems_bf, masks,
                                           align_out, c_bf);
    out_gemm<<<96, 256, 0, stream>>>(c_bf, inputs_bf, Wout_bf, bout, attn_h);
}